// Round 17
// baseline (320.487 us; speedup 1.0000x reference)
//
#include <hip/hip_runtime.h>

typedef _Float16 f16;
typedef __attribute__((ext_vector_type(4))) _Float16 f16x4;
typedef __attribute__((ext_vector_type(8))) _Float16 f16x8;
typedef __attribute__((ext_vector_type(4))) float f32x4;

#define B_ 8192
#define D_ 784
#define H_ 1024
#define L_ 128
#define T_ 10
#define KP1 896          // Xp row stride (D padded)
#define MAXTILES (B_/128 + T_)   // 74 (128-row tile map)
#define PADROWS 256
#define BOFF 32768       // B region base (after 2 A buffers)

// ctrl int indices
#define C_COUNT 0
#define C_CURS 16
#define C_OFFS 32
#define C_NTILES 49
#define C_TTASK 64
#define C_TROW 160

__global__ void k_init(int* ctrl) {
    if (threadIdx.x < 64) ctrl[threadIdx.x] = 0;
}

__global__ void k_count(const int* __restrict__ task, int* __restrict__ ctrl) {
    int b = blockIdx.x * 256 + threadIdx.x;
    if (b < B_) atomicAdd(&ctrl[C_COUNT + task[b]], 1);
}

__global__ void k_scan(int* ctrl) {
    if (threadIdx.x == 0 && blockIdx.x == 0) {
        int off = 0;
        ctrl[C_OFFS] = 0;
        for (int t = 0; t < T_; ++t) { off += ctrl[C_COUNT + t]; ctrl[C_OFFS + t + 1] = off; }
        int nt = 0;
        for (int t = 0; t < T_; ++t)
            for (int r = ctrl[C_OFFS + t]; r < ctrl[C_OFFS + t + 1]; r += 128) {
                ctrl[C_TTASK + nt] = t; ctrl[C_TROW + nt] = r; ++nt;
            }
        ctrl[C_NTILES] = nt;
    }
}

__global__ void k_scatter(const int* __restrict__ task, int* __restrict__ ctrl, int* __restrict__ perm) {
    int b = blockIdx.x * 256 + threadIdx.x;
    if (b >= B_) return;
    int t = task[b];
    int i = ctrl[C_OFFS + t] + atomicAdd(&ctrl[C_CURS + t], 1);
    perm[i] = b;
}

__global__ void k_gather_x(const float* __restrict__ x, const int* __restrict__ perm, f16* __restrict__ Xp) {
    int i = blockIdx.x;
    int r = perm[i];
    int c = threadIdx.x * 4;
    if (c >= KP1) return;
    f16x4 o = (f16x4){0, 0, 0, 0};
    if (c < D_) {
        float4 v = *(const float4*)(x + (long)r * D_ + c);
        o[0] = (f16)v.x; o[1] = (f16)v.y; o[2] = (f16)v.z; o[3] = (f16)v.w;
    }
    *(f16x4*)(Xp + (long)i * KP1 + c) = o;
}

// z = mu + exp(ls) * eps  (permuted rows)
__global__ void k_z(const float* __restrict__ mu, const float* __restrict__ ls,
                    const float* __restrict__ eps, const int* __restrict__ perm,
                    f16* __restrict__ Z) {
    long gid = (long)blockIdx.x * 256 + threadIdx.x;
    int i = (int)(gid >> 7), c = (int)(gid & 127);
    int r = perm[i];
    float m = mu[(long)r * L_ + c];
    float l = ls[(long)r * L_ + c];
    Z[(long)i * L_ + c] = (f16)(m + __expf(l) * eps[(long)r * L_ + c]);
}

// ---------------------------------------------------------------------------
// 128M x 64N GEMM, fused fp32->f16 weight conversion, SYNCTHREADS-ONLY sync
// (r15/r16's counted-vmcnt protocol abandoned: unverifiable at source level).
// A: f16 [rows][lda], global_load_lds into DOUBLE-buffered LDS (2x16KB),
//    staged for kt+1 at the top of kt's compute phase -> full coverage.
// B: fp32 natural [K][N] -> regs (LOADB kt+1 issued at compute top, covered)
//    -> convert+transpose -> swizzled ds_write AFTER the post-compute barrier.
// Every barrier is __syncthreads (vmcnt0+lgkm0+barrier): prefetches are
// drained only at the barrier AFTER their coverage window -> race-free AND
// no exposed global latency in steady state. LDS 40KB -> 4 blocks/CU exactly.
// B clamped loads: benign (enc1 k>=784 x A-zero-pad; head n>=784 not stored).
// ---------------------------------------------------------------------------
template <int EPI, bool GROUPED>
__global__ __launch_bounds__(256, 4)
void k_gemmG(const f16* __restrict__ A, int lda,
             const float* __restrict__ W, long wstride,
             const float* __restrict__ bias, int bstride,
             int NI, int Kreal, int Nreal, int ntn,
             f16* __restrict__ outF16, float* __restrict__ o0, float* __restrict__ o1,
             const int* __restrict__ ctrl, const int* __restrict__ perm) {
    __shared__ char lds[40960];   // A buf0 @0, A buf1 @16384, B @32768 (8KB)
    int tid = threadIdx.x, lane = tid & 63;
    int wave = tid >> 6, wm = wave >> 1, wn = wave & 1;

    // bijective XCD swizzle (m204)
    int nwg = gridDim.x, orig = blockIdx.x;
    int qq = nwg >> 3, rr8 = nwg & 7, xcd = orig & 7, idx = orig >> 3;
    int wgid = (xcd < rr8 ? xcd * (qq + 1) : rr8 * (qq + 1) + (xcd - rr8) * qq) + idx;
    int tm = wgid / ntn, tn = wgid - tm * ntn;

    int t, row0, mrows;
    if (GROUPED) {
        if (tm >= ctrl[C_NTILES]) return;
        t = ctrl[C_TTASK + tm];
        row0 = ctrl[C_TROW + tm];
        mrows = min(128, ctrl[C_OFFS + t + 1] - row0);
    } else {
        t = 0; row0 = tm * 128; mrows = 128;
    }
    const float* Wt = W + (long)t * wstride;
    const float* bt = bias + (long)t * bstride;
    int n0 = tn * 64;

    // ---- A staging invariants (r11 verified) ----
    int rowc = tid >> 3;
    long srcElem = (long)rowc * lda + (((tid & 7) ^ (rowc & 7)) << 3);
    int dstOff = wave << 10;
    const f16* Abase = A + (long)row0 * lda + srcElem;

    auto STAGEA = [&](int kt) {
        const f16* a = Abase + kt * 64;
        char* base = lds + (kt & 1) * 16384;
#pragma unroll
        for (int c = 0; c < 4; ++c)
            __builtin_amdgcn_global_load_lds(
                (const __attribute__((address_space(1))) unsigned int*)(a + (long)c * 32 * lda),
                (__attribute__((address_space(3))) unsigned int*)(base + c * 4096 + dstOff), 16, 0, 0);
    };

    // ---- B staging invariants (swizzled write == r11 read layout) ----
    int bq = tid >> 4;           // k-quad 0..15
    int bs = tid & 15;           // n-quad
    int bn = n0 + 4 * bs;
    const float* Wb = Wt + min(bn, Nreal - 4);   // clamped, 16B-aligned (Nreal%4==0)
    int Kc = Kreal - 1;
    int nl = 4 * bs;
    char* bw0 = lds + BOFF + (nl + 0) * 128 + ((((bq >> 1)) ^ ((nl + 0) & 7)) << 4) + ((bq & 1) << 3);
    char* bw1 = lds + BOFF + (nl + 1) * 128 + ((((bq >> 1)) ^ ((nl + 1) & 7)) << 4) + ((bq & 1) << 3);
    char* bw2 = lds + BOFF + (nl + 2) * 128 + ((((bq >> 1)) ^ ((nl + 2) & 7)) << 4) + ((bq & 1) << 3);
    char* bw3 = lds + BOFF + (nl + 3) * 128 + ((((bq >> 1)) ^ ((nl + 3) & 7)) << 4) + ((bq & 1) << 3);

    float4 v0, v1, v2, v3;
    auto LOADB = [&](int kt) {   // unconditional, clamped: branchless
        int kb = kt * 64 + 4 * bq;
        v0 = *(const float4*)(Wb + (long)min(kb + 0, Kc) * Nreal);
        v1 = *(const float4*)(Wb + (long)min(kb + 1, Kc) * Nreal);
        v2 = *(const float4*)(Wb + (long)min(kb + 2, Kc) * Nreal);
        v3 = *(const float4*)(Wb + (long)min(kb + 3, Kc) * Nreal);
    };
    auto WRITEB = [&]() {
        f16x4 c0 = {(f16)v0.x, (f16)v1.x, (f16)v2.x, (f16)v3.x};
        f16x4 c1 = {(f16)v0.y, (f16)v1.y, (f16)v2.y, (f16)v3.y};
        f16x4 c2 = {(f16)v0.z, (f16)v1.z, (f16)v2.z, (f16)v3.z};
        f16x4 c3 = {(f16)v0.w, (f16)v1.w, (f16)v2.w, (f16)v3.w};
        *(f16x4*)bw0 = c0;
        *(f16x4*)bw1 = c1;
        *(f16x4*)bw2 = c2;
        *(f16x4*)bw3 = c3;
    };

    f32x4 acc[4][2];
#pragma unroll
    for (int i = 0; i < 4; ++i)
#pragma unroll
        for (int j = 0; j < 2; ++j) acc[i][j] = (f32x4){0.f, 0.f, 0.f, 0.f};

    // read addressing (r11 verified)
    int slot0 = ((lane >> 4) ^ (lane & 7)) << 4;
    int aoff = (wm * 64 + (lane & 15)) * 128 + slot0;
    const char* bptr = lds + BOFF + (wn * 32 + (lane & 15)) * 128 + slot0;

    // prologue: A(0) + B(0) ready
    STAGEA(0);
    LOADB(0);
    __syncthreads();      // A(0) landed; v regs ready
    WRITEB();
    __syncthreads();      // B(0) visible

    for (int kt = 0; kt < NI; ++kt) {
        bool have = (kt + 1 < NI);
        if (have) {
            STAGEA(kt + 1);   // into abuf[(kt+1)&1]; covered by compute below
            LOADB(kt + 1);    // fp32 B -> regs; covered by compute below
        }

        const char* aptr = lds + (kt & 1) * 16384 + aoff;
#pragma unroll
        for (int ks = 0; ks < 2; ++ks) {
            int xo = ((slot0 ^ (ks * 64)) - slot0);
            f16x8 af[4], bf[2];
#pragma unroll
            for (int mi = 0; mi < 4; ++mi)
                af[mi] = *(const f16x8*)(aptr + mi * 2048 + xo);
#pragma unroll
            for (int nj = 0; nj < 2; ++nj)
                bf[nj] = *(const f16x8*)(bptr + nj * 2048 + xo);
#pragma unroll
            for (int mi = 0; mi < 4; ++mi)
#pragma unroll
                for (int nj = 0; nj < 2; ++nj)
                    acc[mi][nj] = __builtin_amdgcn_mfma_f32_16x16x32_f16(af[mi], bf[nj], acc[mi][nj], 0, 0, 0);
        }
        __syncthreads();      // drains A(kt+1)+B(kt+1) (covered); read-protect B
        if (have) {
            WRITEB();         // B(kt+1) into LDS (reads of B(kt) all done)
            __syncthreads();  // B(kt+1) visible (cheap: only lgkm outstanding)
        }
    }

    // epilogue
    int cq = lane >> 4, cr = lane & 15;
#pragma unroll
    for (int mi = 0; mi < 4; ++mi) {
#pragma unroll
        for (int nj = 0; nj < 2; ++nj) {
#pragma unroll
            for (int reg = 0; reg < 4; ++reg) {
                int rl = wm * 64 + mi * 16 + cq * 4 + reg;
                if (rl >= mrows) continue;
                int gcol = n0 + wn * 32 + nj * 16 + cr;
                if (gcol >= Nreal) continue;
                float v = acc[mi][nj][reg] + bt[gcol];
                int grow = row0 + rl;
                if (EPI == 0) {
                    outF16[(long)grow * H_ + gcol] = (f16)(v > 0.f ? v : 0.f);
                } else if (EPI == 1) {
                    int r = perm[grow];
                    if (gcol < L_) o0[(long)r * L_ + gcol] = v;
                    else o1[(long)r * L_ + (gcol - L_)] = v;
                } else {
                    o0[(long)perm[grow] * D_ + gcol] = 1.f / (1.f + __expf(-v));
                }
            }
        }
    }
}

extern "C" void kernel_launch(void* const* d_in, const int* in_sizes, int n_in,
                              void* d_out, int out_size, void* d_ws, size_t ws_size,
                              hipStream_t stream) {
    const float* x   = (const float*)d_in[0];
    const float* eps = (const float*)d_in[1];
    const float* eW1 = (const float*)d_in[2];
    const float* eb1 = (const float*)d_in[3];
    const float* eW2 = (const float*)d_in[4];
    const float* eb2 = (const float*)d_in[5];
    const float* eW3 = (const float*)d_in[6];
    const float* eb3 = (const float*)d_in[7];
    const float* dW1 = (const float*)d_in[8];
    const float* db1 = (const float*)d_in[9];
    const float* dW2 = (const float*)d_in[10];
    const float* db2 = (const float*)d_in[11];
    const float* hW  = (const float*)d_in[12];
    const float* hb  = (const float*)d_in[13];
    const int* task  = (const int*)d_in[14];

    float* out = (float*)d_out;
    float* recon = out;
    float* mu = out + (size_t)B_ * D_;
    float* ls = mu + (size_t)B_ * L_;

    char* w = (char*)d_ws;
    size_t o = 0;
    auto alloc = [&](size_t bytes) -> char* {
        char* p = w + o;
        o = (o + bytes + 255) & ~(size_t)255;
        return p;
    };
    int* ctrl  = (int*)alloc(4096);
    int* perm  = (int*)alloc((size_t)B_ * 4);
    f16* Xp    = (f16*)alloc((size_t)(B_ + PADROWS) * KP1 * 2);
    f16* H1    = (f16*)alloc((size_t)(B_ + PADROWS) * H_ * 2);
    f16* H2    = (f16*)alloc((size_t)(B_ + PADROWS) * H_ * 2);
    f16* Z     = (f16*)alloc((size_t)(B_ + PADROWS) * L_ * 2);
    if (o > ws_size) return;

    k_init<<<1, 64, 0, stream>>>(ctrl);
    k_count<<<B_ / 256, 256, 0, stream>>>(task, ctrl);
    k_scan<<<1, 1, 0, stream>>>(ctrl);
    k_scatter<<<B_ / 256, 256, 0, stream>>>(task, ctrl, perm);
    k_gather_x<<<B_, 256, 0, stream>>>(x, perm, Xp);

    int gridG  = MAXTILES * 16;    // 1184 (grouped, 16 N-tiles of 64)
    int gridG3 = MAXTILES * 4;     // 296 (enc3, N=256)
    int gridD  = (B_ / 128) * 16;  // 1024 (dense)
    int gridH  = MAXTILES * 13;    // 962 (head, 13 N-tiles cover 784..832)

    // encoder layer 1: Xp(lda=896) @ eW1(fp32 784x1024) -> relu -> H1
    k_gemmG<0, true><<<gridG, 256, 0, stream>>>(
        Xp, KP1, eW1, (long)D_ * H_, eb1, H_, 13, D_, H_, 16,
        H1, nullptr, nullptr, ctrl, perm);
    // encoder layer 2: H1 @ eW2 -> relu -> H2
    k_gemmG<0, true><<<gridG, 256, 0, stream>>>(
        H1, H_, eW2, (long)H_ * H_, eb2, H_, 16, H_, H_, 16,
        H2, nullptr, nullptr, ctrl, perm);
    // encoder layer 3: H2 @ eW3 -> mu/ls perm-scatter
    k_gemmG<1, true><<<gridG3, 256, 0, stream>>>(
        H2, H_, eW3, (long)H_ * 256, eb3, 256, 16, H_, 256, 4,
        nullptr, mu, ls, ctrl, perm);
    // z = mu + exp(ls)*eps
    k_z<<<(B_ * L_) / 256, 256, 0, stream>>>(mu, ls, eps, perm, Z);
    // decoder layer 1: Z(lda=128) @ dW1 -> relu -> H1
    k_gemmG<0, false><<<gridD, 256, 0, stream>>>(
        Z, L_, dW1, 0, db1, 0, 2, L_, H_, 16,
        H1, nullptr, nullptr, ctrl, perm);
    // decoder layer 2: H1 @ dW2 -> relu -> H2
    k_gemmG<0, false><<<gridD, 256, 0, stream>>>(
        H1, H_, dW2, 0, db2, 0, 16, H_, H_, 16,
        H2, nullptr, nullptr, ctrl, perm);
    // head: H2 @ hW -> sigmoid -> recon (perm-scatter fp32)
    k_gemmG<2, true><<<gridH, 256, 0, stream>>>(
        H2, H_, hW, (long)H_ * D_, hb, D_, 16, H_, D_, 13,
        nullptr, recon, nullptr, ctrl, perm);
}